// Round 1
// baseline (691.803 us; speedup 1.0000x reference)
//
#include <hip/hip_runtime.h>

#define NN 8192
#define HH 128
#define JSPLIT 16
#define SEG (NN / JSPLIT)      // 512 j's per segment
#define CHUNKS (SEG / 32)      // 16 K=32 chunks per segment

typedef float f32x4 __attribute__((ext_vector_type(4)));
typedef short bf16x8 __attribute__((ext_vector_type(8)));
typedef unsigned short u16;
typedef unsigned int u32;

__device__ __forceinline__ u16 f2bf(float f) {
    u32 u = __float_as_uint(f);
    u32 r = (u + 0x7FFFu + ((u >> 16) & 1u)) >> 16;   // RNE, inputs are finite
    return (u16)r;
}

// ---------------------------------------------------------------------------
// K1: Wh = node_fea @ W_w.T + W_b   (f32, LDS double-transpose for conflict-free
// b64/b128 reads). Block: 256 thr, 32 rows. Grid: 256.
// ---------------------------------------------------------------------------
__global__ __launch_bounds__(256) void k_wh(const float* __restrict__ X,
                                            const float* __restrict__ Ww,
                                            const float* __restrict__ Wb,
                                            float* __restrict__ Wh) {
    __shared__ float xT[128][38];   // [k][row], stride 38 floats (8B-aligned b64 reads)
    __shared__ float wT[128][68];   // [k][col-half], stride 68 floats (16B-aligned b128)
    const int tid = threadIdx.x;
    const int r0 = blockIdx.x * 32;

    // stage X rows transposed: xT[k][r]
#pragma unroll
    for (int p = 0; p < 4; ++p) {
        int idx = p * 256 + tid;
        int r = idx >> 5, kq = idx & 31;
        float4 v = *(const float4*)&X[(r0 + r) * HH + kq * 4];
        xT[kq * 4 + 0][r] = v.x; xT[kq * 4 + 1][r] = v.y;
        xT[kq * 4 + 2][r] = v.z; xT[kq * 4 + 3][r] = v.w;
    }
    const int rg = tid >> 4;   // 0..15 -> 2 rows each
    const int cg = tid & 15;   // 0..15 -> 4 cols each (within 64-col half)

    for (int ch = 0; ch < 2; ++ch) {
        __syncthreads();   // protects wT reuse (and xT on first iter)
#pragma unroll
        for (int p = 0; p < 8; ++p) {
            int idx = p * 256 + tid;
            int cc = idx >> 5, kq = idx & 31;
            float4 v = *(const float4*)&Ww[(ch * 64 + cc) * HH + kq * 4];
            wT[kq * 4 + 0][cc] = v.x; wT[kq * 4 + 1][cc] = v.y;
            wT[kq * 4 + 2][cc] = v.z; wT[kq * 4 + 3][cc] = v.w;
        }
        __syncthreads();
        float acc0[4] = {0.f, 0.f, 0.f, 0.f};
        float acc1[4] = {0.f, 0.f, 0.f, 0.f};
#pragma unroll 4
        for (int k = 0; k < 128; ++k) {
            float2 xv = *(const float2*)&xT[k][rg * 2];
            f32x4 wv = *(const f32x4*)&wT[k][cg * 4];
#pragma unroll
            for (int j = 0; j < 4; ++j) {
                acc0[j] += xv.x * wv[j];
                acc1[j] += xv.y * wv[j];
            }
        }
        f32x4 bv = *(const f32x4*)&Wb[ch * 64 + cg * 4];
        f32x4 o0 = {acc0[0] + bv[0], acc0[1] + bv[1], acc0[2] + bv[2], acc0[3] + bv[3]};
        f32x4 o1 = {acc1[0] + bv[0], acc1[1] + bv[1], acc1[2] + bv[2], acc1[3] + bv[3]};
        *(f32x4*)&Wh[(r0 + rg * 2 + 0) * HH + ch * 64 + cg * 4] = o0;
        *(f32x4*)&Wh[(r0 + rg * 2 + 1) * HH + ch * 64 + cg * 4] = o1;
    }
}

// ---------------------------------------------------------------------------
// K1c: WhT[c][r] = bf16(Wh[r][c])  (transpose via LDS tile)  +  Whi/Whj row dots
// Block: 256 thr, 64 rows. Grid: 128.
// ---------------------------------------------------------------------------
__global__ __launch_bounds__(256) void k_tr(const float* __restrict__ Wh,
                                            const float* __restrict__ a1,
                                            const float* __restrict__ a2,
                                            u16* __restrict__ WhT,
                                            float* __restrict__ Whi,
                                            float* __restrict__ Whj) {
    __shared__ u16 tb[128][72];   // [col][row], padded
    const int tid = threadIdx.x;
    const int r0 = blockIdx.x * 64;
    const int c4 = tid & 31;     // col quad
    const int rloc = tid >> 5;   // 0..7
    f32x4 a1v = *(const f32x4*)&a1[c4 * 4];
    f32x4 a2v = *(const f32x4*)&a2[c4 * 4];
#pragma unroll
    for (int p = 0; p < 8; ++p) {
        int r = p * 8 + rloc;   // 0..63
        f32x4 v = *(const f32x4*)&Wh[(r0 + r) * HH + c4 * 4];
        tb[c4 * 4 + 0][r] = f2bf(v[0]); tb[c4 * 4 + 1][r] = f2bf(v[1]);
        tb[c4 * 4 + 2][r] = f2bf(v[2]); tb[c4 * 4 + 3][r] = f2bf(v[3]);
        float pi = v[0] * a1v[0] + v[1] * a1v[1] + v[2] * a1v[2] + v[3] * a1v[3];
        float pj = v[0] * a2v[0] + v[1] * a2v[1] + v[2] * a2v[2] + v[3] * a2v[3];
        // reduce across the 32 threads (= lanes) sharing this row
#pragma unroll
        for (int s = 16; s >= 1; s >>= 1) {
            pi += __shfl_xor(pi, s);
            pj += __shfl_xor(pj, s);
        }
        if (c4 == 0) { Whi[r0 + r] = pi; Whj[r0 + r] = pj; }
    }
    __syncthreads();
    const int c = tid >> 1, half = tid & 1;
#pragma unroll
    for (int q = 0; q < 4; ++q) {
        int4 v = *(const int4*)&tb[c][half * 32 + q * 8];
        *(int4*)&WhT[c * NN + r0 + half * 32 + q * 8] = v;
    }
}

// ---------------------------------------------------------------------------
// K2: fused mask + exp(leakyrelu(rank-1 scores)) + P@Wh via MFMA, j-split
// partials. P is built directly in the 16x16x32 A-fragment layout:
//   A[i][k]: i = lane&15, k = (lane>>4)*8 + e  -> 2x int4 adj loads per frag.
//   B[k][n]: n = lane&15, k = (lane>>4)*8 + e  -> one 16B load from WhT.
// Block: 256 thr (4 waves x 32 rows = 128 rows). Grid: (64 row-blocks, 16 segs).
// ---------------------------------------------------------------------------
#define PEL(whiv, av, wjv, zz, oute)                                      \
    {                                                                     \
        float s_ = (whiv) + (wjv);                                        \
        s_ = s_ > 0.f ? s_ : 0.2f * s_;                                   \
        float w_ = ((av) > 0) ? __expf(s_) : 0.f;                         \
        zz += w_;                                                         \
        oute = (short)f2bf(w_);                                           \
    }

__global__ __launch_bounds__(256) void k_attn(const int* __restrict__ adj,
                                              const u16* __restrict__ WhT,
                                              const float* __restrict__ Whi,
                                              const float* __restrict__ Whj,
                                              float* __restrict__ accP,
                                              float* __restrict__ Zp) {
    const int tid = threadIdx.x;
    const int wave = tid >> 6, lane = tid & 63;
    const int m = lane & 15, g = lane >> 4;
    const int kbase = g * 8;
    const int r0 = blockIdx.x * 128 + wave * 32;
    const int j0b = blockIdx.y * SEG;
    const int row0 = r0 + m, row1 = r0 + 16 + m;
    const float whi0 = Whi[row0], whi1 = Whi[row1];
    const int* arow0 = adj + row0 * NN + j0b;
    const int* arow1 = adj + row1 * NN + j0b;
    const float* wjp = Whj + j0b;
    const u16* bbase = WhT + m * NN + j0b;

    f32x4 acc[2][8];
#pragma unroll
    for (int a = 0; a < 2; ++a)
#pragma unroll
        for (int b = 0; b < 8; ++b) acc[a][b] = (f32x4){0.f, 0.f, 0.f, 0.f};
    float z0 = 0.f, z1 = 0.f;

    for (int cch = 0; cch < CHUNKS; ++cch) {
        const int jo = cch * 32 + kbase;
        f32x4 wj0 = *(const f32x4*)&wjp[jo];
        f32x4 wj1 = *(const f32x4*)&wjp[jo + 4];
        int4 a00 = *(const int4*)&arow0[jo];
        int4 a01 = *(const int4*)&arow0[jo + 4];
        int4 a10 = *(const int4*)&arow1[jo];
        int4 a11 = *(const int4*)&arow1[jo + 4];
        bf16x8 pa0, pa1;
        PEL(whi0, a00.x, wj0[0], z0, pa0[0]); PEL(whi0, a00.y, wj0[1], z0, pa0[1]);
        PEL(whi0, a00.z, wj0[2], z0, pa0[2]); PEL(whi0, a00.w, wj0[3], z0, pa0[3]);
        PEL(whi0, a01.x, wj1[0], z0, pa0[4]); PEL(whi0, a01.y, wj1[1], z0, pa0[5]);
        PEL(whi0, a01.z, wj1[2], z0, pa0[6]); PEL(whi0, a01.w, wj1[3], z0, pa0[7]);
        PEL(whi1, a10.x, wj0[0], z1, pa1[0]); PEL(whi1, a10.y, wj0[1], z1, pa1[1]);
        PEL(whi1, a10.z, wj0[2], z1, pa1[2]); PEL(whi1, a10.w, wj0[3], z1, pa1[3]);
        PEL(whi1, a11.x, wj1[0], z1, pa1[4]); PEL(whi1, a11.y, wj1[1], z1, pa1[5]);
        PEL(whi1, a11.z, wj1[2], z1, pa1[6]); PEL(whi1, a11.w, wj1[3], z1, pa1[7]);

        const u16* bp = bbase + jo;   // = WhT[(m)*NN + j0b + cch*32 + kbase]
#pragma unroll
        for (int ct = 0; ct < 8; ++ct) {
            bf16x8 bfr = *(const bf16x8*)(bp + ct * 16 * NN);
            acc[0][ct] = __builtin_amdgcn_mfma_f32_16x16x32_bf16(pa0, bfr, acc[0][ct], 0, 0, 0);
            acc[1][ct] = __builtin_amdgcn_mfma_f32_16x16x32_bf16(pa1, bfr, acc[1][ct], 0, 0, 0);
        }
    }

    // Z: sum the 4 k-groups holding the same row (lanes m, m+16, m+32, m+48)
    z0 += __shfl_xor(z0, 16); z0 += __shfl_xor(z0, 32);
    z1 += __shfl_xor(z1, 16); z1 += __shfl_xor(z1, 32);
    if (lane < 16) {
        Zp[blockIdx.y * NN + r0 + lane] = z0;
        Zp[blockIdx.y * NN + r0 + 16 + lane] = z1;
    }
    // store partial numerators; C/D layout: col = lane&15, row = (lane>>4)*4+reg
    const long base = (long)blockIdx.y * NN * HH;
#pragma unroll
    for (int it = 0; it < 2; ++it)
#pragma unroll
        for (int ct = 0; ct < 8; ++ct)
#pragma unroll
            for (int reg = 0; reg < 4; ++reg) {
                int row = r0 + it * 16 + g * 4 + reg;
                accP[base + row * HH + ct * 16 + m] = acc[it][ct][reg];
            }
}

// ---------------------------------------------------------------------------
// K3: out[i][c] = sum_s accP[s][i][c] / sum_s Zp[s][i] + Wh[i][c]
// ---------------------------------------------------------------------------
__global__ __launch_bounds__(256) void k_red(const float* __restrict__ accP,
                                             const float* __restrict__ Zp,
                                             const float* __restrict__ Wh,
                                             float* __restrict__ out) {
    const int gidx = blockIdx.x * 256 + threadIdx.x;   // 0..262143
    const int i = gidx >> 5;
    const int c4 = (gidx & 31) * 4;
    f32x4 s = {0.f, 0.f, 0.f, 0.f};
    float z = 0.f;
#pragma unroll
    for (int sg = 0; sg < JSPLIT; ++sg) {
        s += *(const f32x4*)&accP[sg * (NN * HH) + i * HH + c4];
        z += Zp[sg * NN + i];
    }
    f32x4 whv = *(const f32x4*)&Wh[i * HH + c4];
    f32x4 o = s * (1.f / z) + whv;
    *(f32x4*)&out[i * HH + c4] = o;
}

// ---------------------------------------------------------------------------
// K4: edge_fea passthrough copy (float4 grid-stride)
// ---------------------------------------------------------------------------
__global__ __launch_bounds__(256) void k_copy(const f32x4* __restrict__ src,
                                              f32x4* __restrict__ dst, int n4) {
    int idx = blockIdx.x * 256 + threadIdx.x;
    const int stride = gridDim.x * 256;
    for (; idx < n4; idx += stride) dst[idx] = src[idx];
}

// ---------------------------------------------------------------------------
extern "C" void kernel_launch(void* const* d_in, const int* in_sizes, int n_in,
                              void* d_out, int out_size, void* d_ws, size_t ws_size,
                              hipStream_t stream) {
    const float* node = (const float*)d_in[0];
    const float* edge = (const float*)d_in[1];
    const int*   adj  = (const int*)d_in[2];
    const float* Ww   = (const float*)d_in[3];
    const float* Wb   = (const float*)d_in[4];
    const float* a1   = (const float*)d_in[5];
    const float* a2   = (const float*)d_in[6];
    float* out = (float*)d_out;

    // scratch layout (bytes):
    //   Wh f32        @ 0         (4 MiB)
    //   Whi f32       @ 4 MiB     (32 KiB)
    //   Whj f32       @ +32 KiB   (32 KiB)
    //   Zp  f32       @ +64 KiB   (512 KiB)
    //   accP f32      @ +576 KiB  (64 MiB)
    //   WhT bf16      @ +64.5625M (2 MiB)
    const size_t OFF_WH  = 0;
    const size_t OFF_WHI = (size_t)4 * 1024 * 1024;
    const size_t OFF_WHJ = OFF_WHI + 32 * 1024;
    const size_t OFF_ZP  = OFF_WHJ + 32 * 1024;
    const size_t OFF_AP  = OFF_ZP + 512 * 1024;
    const size_t OFF_WHT = OFF_AP + (size_t)64 * 1024 * 1024;
    const size_t NEED    = OFF_WHT + (size_t)2 * 1024 * 1024;   // ~70.6 MiB

    // fall back to the edge region of d_out (268 MB, overwritten last) if ws is small
    char* scratch = (ws_size >= NEED) ? (char*)d_ws
                                      : (char*)d_out + (size_t)NN * HH * 4;
    float* Wh   = (float*)(scratch + OFF_WH);
    float* Whi  = (float*)(scratch + OFF_WHI);
    float* Whj  = (float*)(scratch + OFF_WHJ);
    float* Zp   = (float*)(scratch + OFF_ZP);
    float* accP = (float*)(scratch + OFF_AP);
    u16*   WhT  = (u16*)(scratch + OFF_WHT);

    k_wh<<<dim3(256), 256, 0, stream>>>(node, Ww, Wb, Wh);
    k_tr<<<dim3(128), 256, 0, stream>>>(Wh, a1, a2, WhT, Whi, Whj);
    k_attn<<<dim3(64, JSPLIT), 256, 0, stream>>>(adj, WhT, Whi, Whj, accP, Zp);
    k_red<<<dim3(1024), 256, 0, stream>>>(accP, Zp, Wh, out);
    // edge passthrough LAST (it overwrites the d_out scratch fallback region)
    k_copy<<<dim3(4096), 256, 0, stream>>>((const f32x4*)edge,
                                           (f32x4*)(out + (size_t)NN * HH),
                                           NN * NN / 4);
}

// Round 2
// 665.257 us; speedup vs baseline: 1.0399x; 1.0399x over previous
//
#include <hip/hip_runtime.h>

#define NN 8192
#define HH 128
#define JSPLIT 8
#define SEG (NN / JSPLIT)          // 1024 j's per segment
#define CHUNKS (SEG / 32)          // 32 K=32 chunks per segment
#define COPY_BLOCKS 256
#define ATTN_BLOCKS (64 * JSPLIT)  // 512
#define COPY_PER_BLOCK ((NN * NN / 4) / COPY_BLOCKS)  // 65536 f32x4 per block

typedef float f32x4 __attribute__((ext_vector_type(4)));
typedef short bf16x8 __attribute__((ext_vector_type(8)));
typedef unsigned short u16;
typedef unsigned int u32;

__device__ __forceinline__ u16 f2bf(float f) {
    u32 u = __float_as_uint(f);
    u32 r = (u + 0x7FFFu + ((u >> 16) & 1u)) >> 16;   // RNE, inputs finite
    return (u16)r;
}

// ---------------------------------------------------------------------------
// K_pre: Wh = X @ W.T + b (f32), fused with:
//   - WhT (bf16, transposed [col][row]) for MFMA B-fragments
//   - Whi = Wh@a1.T, Whj = Wh@a2.T
// Block: 256 thr, 32 rows. Grid: 256.
// ---------------------------------------------------------------------------
__global__ __launch_bounds__(256) void k_pre(const float* __restrict__ X,
                                             const float* __restrict__ Ww,
                                             const float* __restrict__ Wb,
                                             const float* __restrict__ a1,
                                             const float* __restrict__ a2,
                                             float* __restrict__ Wh,
                                             u16* __restrict__ WhT,
                                             float* __restrict__ Whi,
                                             float* __restrict__ Whj) {
    __shared__ float xT[128][38];   // [k][row]
    __shared__ float wT[128][68];   // [k][col-half]
    __shared__ u16 tb[128][40];     // [col][row] bf16, 16B-aligned rows (80B stride)
    const int tid = threadIdx.x;
    const int r0 = blockIdx.x * 32;

#pragma unroll
    for (int p = 0; p < 4; ++p) {
        int idx = p * 256 + tid;
        int r = idx >> 5, kq = idx & 31;
        float4 v = *(const float4*)&X[(r0 + r) * HH + kq * 4];
        xT[kq * 4 + 0][r] = v.x; xT[kq * 4 + 1][r] = v.y;
        xT[kq * 4 + 2][r] = v.z; xT[kq * 4 + 3][r] = v.w;
    }
    const int rg = tid >> 4;   // 0..15 -> rows rg*2, rg*2+1
    const int cg = tid & 15;   // 0..15 -> 4 cols per 64-col half
    float pi0 = 0.f, pi1 = 0.f, pj0 = 0.f, pj1 = 0.f;

    for (int ch = 0; ch < 2; ++ch) {
        __syncthreads();   // xT ready (ch=0) / wT reusable (ch=1)
#pragma unroll
        for (int p = 0; p < 8; ++p) {
            int idx = p * 256 + tid;
            int cc = idx >> 5, kq = idx & 31;
            float4 v = *(const float4*)&Ww[(ch * 64 + cc) * HH + kq * 4];
            wT[kq * 4 + 0][cc] = v.x; wT[kq * 4 + 1][cc] = v.y;
            wT[kq * 4 + 2][cc] = v.z; wT[kq * 4 + 3][cc] = v.w;
        }
        __syncthreads();
        float acc0[4] = {0.f, 0.f, 0.f, 0.f};
        float acc1[4] = {0.f, 0.f, 0.f, 0.f};
#pragma unroll 4
        for (int k = 0; k < 128; ++k) {
            float2 xv = *(const float2*)&xT[k][rg * 2];
            f32x4 wv = *(const f32x4*)&wT[k][cg * 4];
#pragma unroll
            for (int j = 0; j < 4; ++j) {
                acc0[j] += xv.x * wv[j];
                acc1[j] += xv.y * wv[j];
            }
        }
        f32x4 bv  = *(const f32x4*)&Wb[ch * 64 + cg * 4];
        f32x4 a1v = *(const f32x4*)&a1[ch * 64 + cg * 4];
        f32x4 a2v = *(const f32x4*)&a2[ch * 64 + cg * 4];
        f32x4 o0 = {acc0[0] + bv[0], acc0[1] + bv[1], acc0[2] + bv[2], acc0[3] + bv[3]};
        f32x4 o1 = {acc1[0] + bv[0], acc1[1] + bv[1], acc1[2] + bv[2], acc1[3] + bv[3]};
        *(f32x4*)&Wh[(r0 + rg * 2 + 0) * HH + ch * 64 + cg * 4] = o0;
        *(f32x4*)&Wh[(r0 + rg * 2 + 1) * HH + ch * 64 + cg * 4] = o1;
#pragma unroll
        for (int j = 0; j < 4; ++j) {
            tb[ch * 64 + cg * 4 + j][rg * 2 + 0] = f2bf(o0[j]);
            tb[ch * 64 + cg * 4 + j][rg * 2 + 1] = f2bf(o1[j]);
        }
#pragma unroll
        for (int j = 0; j < 4; ++j) {
            pi0 += o0[j] * a1v[j]; pj0 += o0[j] * a2v[j];
            pi1 += o1[j] * a1v[j]; pj1 += o1[j] * a2v[j];
        }
    }
    // reduce pi/pj across the 16-lane cg group (lanes rg*16..rg*16+15 of wave)
#pragma unroll
    for (int s = 8; s >= 1; s >>= 1) {
        pi0 += __shfl_xor(pi0, s); pj0 += __shfl_xor(pj0, s);
        pi1 += __shfl_xor(pi1, s); pj1 += __shfl_xor(pj1, s);
    }
    if (cg == 0) {
        Whi[r0 + rg * 2 + 0] = pi0; Whj[r0 + rg * 2 + 0] = pj0;
        Whi[r0 + rg * 2 + 1] = pi1; Whj[r0 + rg * 2 + 1] = pj1;
    }
    __syncthreads();
    // write WhT columns: 2 threads per column, 16 rows (2x int4) each
    const int c = tid >> 1, h = tid & 1;
#pragma unroll
    for (int q = 0; q < 2; ++q) {
        int4 v = *(const int4*)&tb[c][h * 16 + q * 8];
        *(int4*)&WhT[(size_t)c * NN + r0 + h * 16 + q * 8] = v;
    }
}

// ---------------------------------------------------------------------------
// K_main: block-role split.
//   bid < 256            : edge passthrough copy slice (memory stream)
//   bid in [256, 768)    : fused mask+exp(leakyrelu(rank-1)) + P@Wh (MFMA),
//                          j-split partials. A-frag built in-register:
//                          A[i][k]: i=lane&15, k=(lane>>4)*8+e.
// Copy blocks dispatch FIRST so both roles are co-resident (mem/compute overlap).
// ---------------------------------------------------------------------------
#define PEL(whiv, av, wjv, zz, oute)                                      \
    {                                                                     \
        float s_ = (whiv) + (wjv);                                        \
        s_ = s_ > 0.f ? s_ : 0.2f * s_;                                   \
        float w_ = ((av) > 0) ? __expf(s_) : 0.f;                         \
        zz += w_;                                                         \
        oute = (short)f2bf(w_);                                           \
    }

__global__ __launch_bounds__(256) void k_main(const int* __restrict__ adj,
                                              const u16* __restrict__ WhT,
                                              const float* __restrict__ Whi,
                                              const float* __restrict__ Whj,
                                              const f32x4* __restrict__ edge,
                                              f32x4* __restrict__ edst,
                                              float* __restrict__ accP,
                                              float* __restrict__ Zp,
                                              int fused_copy) {
    const int bid = blockIdx.x;
    if (bid < COPY_BLOCKS) {
        if (!fused_copy) return;
        const int base = bid * COPY_PER_BLOCK + threadIdx.x;
#pragma unroll 8
        for (int k = 0; k < COPY_PER_BLOCK / 256; ++k)
            edst[base + k * 256] = edge[base + k * 256];
        return;
    }
    const int ab = bid - COPY_BLOCKS;
    const int rb = ab & 63, seg = ab >> 6;
    const int tid = threadIdx.x;
    const int wave = tid >> 6, lane = tid & 63;
    const int m = lane & 15, g = lane >> 4;
    const int kbase = g * 8;
    const int r0 = rb * 128 + wave * 32;
    const int j0b = seg * SEG;
    const int row0 = r0 + m, row1 = r0 + 16 + m;
    const float whi0 = Whi[row0], whi1 = Whi[row1];
    const int* arow0 = adj + (size_t)row0 * NN + j0b;
    const int* arow1 = adj + (size_t)row1 * NN + j0b;
    const float* wjp = Whj + j0b;
    const u16* bbase = WhT + (size_t)m * NN + j0b;

    f32x4 acc[2][8];
#pragma unroll
    for (int a = 0; a < 2; ++a)
#pragma unroll
        for (int b = 0; b < 8; ++b) acc[a][b] = (f32x4){0.f, 0.f, 0.f, 0.f};
    float z0 = 0.f, z1 = 0.f;

    // software-pipelined chunk loop: prefetch next chunk's adj/Whj
    int jo = kbase;
    f32x4 cw0 = *(const f32x4*)&wjp[jo];
    f32x4 cw1 = *(const f32x4*)&wjp[jo + 4];
    int4 c00 = *(const int4*)&arow0[jo];
    int4 c01 = *(const int4*)&arow0[jo + 4];
    int4 c10 = *(const int4*)&arow1[jo];
    int4 c11 = *(const int4*)&arow1[jo + 4];

    for (int cch = 0; cch < CHUNKS; ++cch) {
        const int jn = (cch + 1 < CHUNKS ? cch + 1 : cch) * 32 + kbase;
        f32x4 nw0 = *(const f32x4*)&wjp[jn];
        f32x4 nw1 = *(const f32x4*)&wjp[jn + 4];
        int4 n00 = *(const int4*)&arow0[jn];
        int4 n01 = *(const int4*)&arow0[jn + 4];
        int4 n10 = *(const int4*)&arow1[jn];
        int4 n11 = *(const int4*)&arow1[jn + 4];

        bf16x8 pa0, pa1;
        PEL(whi0, c00.x, cw0[0], z0, pa0[0]); PEL(whi0, c00.y, cw0[1], z0, pa0[1]);
        PEL(whi0, c00.z, cw0[2], z0, pa0[2]); PEL(whi0, c00.w, cw0[3], z0, pa0[3]);
        PEL(whi0, c01.x, cw1[0], z0, pa0[4]); PEL(whi0, c01.y, cw1[1], z0, pa0[5]);
        PEL(whi0, c01.z, cw1[2], z0, pa0[6]); PEL(whi0, c01.w, cw1[3], z0, pa0[7]);
        PEL(whi1, c10.x, cw0[0], z1, pa1[0]); PEL(whi1, c10.y, cw0[1], z1, pa1[1]);
        PEL(whi1, c10.z, cw0[2], z1, pa1[2]); PEL(whi1, c10.w, cw0[3], z1, pa1[3]);
        PEL(whi1, c11.x, cw1[0], z1, pa1[4]); PEL(whi1, c11.y, cw1[1], z1, pa1[5]);
        PEL(whi1, c11.z, cw1[2], z1, pa1[6]); PEL(whi1, c11.w, cw1[3], z1, pa1[7]);

        const u16* bp = bbase + cch * 32 + kbase;
#pragma unroll
        for (int hh = 0; hh < 2; ++hh) {
            bf16x8 bfr[4];
#pragma unroll
            for (int t = 0; t < 4; ++t)
                bfr[t] = *(const bf16x8*)(bp + (size_t)(hh * 4 + t) * 16 * NN);
#pragma unroll
            for (int t = 0; t < 4; ++t) {
                acc[0][hh * 4 + t] = __builtin_amdgcn_mfma_f32_16x16x32_bf16(
                    pa0, bfr[t], acc[0][hh * 4 + t], 0, 0, 0);
                acc[1][hh * 4 + t] = __builtin_amdgcn_mfma_f32_16x16x32_bf16(
                    pa1, bfr[t], acc[1][hh * 4 + t], 0, 0, 0);
            }
        }
        cw0 = nw0; cw1 = nw1;
        c00 = n00; c01 = n01; c10 = n10; c11 = n11;
    }

    // Z: sum across the 4 k-groups holding the same row
    z0 += __shfl_xor(z0, 16); z0 += __shfl_xor(z0, 32);
    z1 += __shfl_xor(z1, 16); z1 += __shfl_xor(z1, 32);
    if (lane < 16) {
        Zp[(size_t)seg * NN + r0 + lane] = z0;
        Zp[(size_t)seg * NN + r0 + 16 + lane] = z1;
    }
    // partial numerators; C/D layout: col = lane&15, row = (lane>>4)*4+reg
    const size_t base = (size_t)seg * NN * HH;
#pragma unroll
    for (int it = 0; it < 2; ++it)
#pragma unroll
        for (int ct = 0; ct < 8; ++ct)
#pragma unroll
            for (int reg = 0; reg < 4; ++reg) {
                int row = r0 + it * 16 + g * 4 + reg;
                accP[base + (size_t)row * HH + ct * 16 + m] = acc[it][ct][reg];
            }
}

// ---------------------------------------------------------------------------
// K_red: out[i][c] = sum_s accP[s][i][c] / sum_s Zp[s][i] + Wh[i][c]
// ---------------------------------------------------------------------------
__global__ __launch_bounds__(256) void k_red(const float* __restrict__ accP,
                                             const float* __restrict__ Zp,
                                             const float* __restrict__ Wh,
                                             float* __restrict__ out) {
    const int gidx = blockIdx.x * 256 + threadIdx.x;   // 0..262143
    const int i = gidx >> 5;
    const int c4 = (gidx & 31) * 4;
    f32x4 s = {0.f, 0.f, 0.f, 0.f};
    float z = 0.f;
#pragma unroll
    for (int sg = 0; sg < JSPLIT; ++sg) {
        s += *(const f32x4*)&accP[(size_t)sg * (NN * HH) + (size_t)i * HH + c4];
        z += Zp[(size_t)sg * NN + i];
    }
    f32x4 whv = *(const f32x4*)&Wh[(size_t)i * HH + c4];
    f32x4 o = s * (1.f / z) + whv;
    *(f32x4*)&out[(size_t)i * HH + c4] = o;
}

// ---------------------------------------------------------------------------
// K_copy: fallback edge passthrough (only if ws too small for fused path)
// ---------------------------------------------------------------------------
__global__ __launch_bounds__(256) void k_copy(const f32x4* __restrict__ src,
                                              f32x4* __restrict__ dst, int n4) {
    int idx = blockIdx.x * 256 + threadIdx.x;
    const int stride = gridDim.x * 256;
    for (; idx < n4; idx += stride) dst[idx] = src[idx];
}

// ---------------------------------------------------------------------------
extern "C" void kernel_launch(void* const* d_in, const int* in_sizes, int n_in,
                              void* d_out, int out_size, void* d_ws, size_t ws_size,
                              hipStream_t stream) {
    const float* node = (const float*)d_in[0];
    const float* edge = (const float*)d_in[1];
    const int*   adj  = (const int*)d_in[2];
    const float* Ww   = (const float*)d_in[3];
    const float* Wb   = (const float*)d_in[4];
    const float* a1   = (const float*)d_in[5];
    const float* a2   = (const float*)d_in[6];
    float* out = (float*)d_out;

    // scratch layout (bytes)
    const size_t OFF_WH  = 0;                                  // 4 MiB
    const size_t OFF_WHI = (size_t)4 * 1024 * 1024;            // 32 KiB
    const size_t OFF_WHJ = OFF_WHI + 32 * 1024;                // 32 KiB
    const size_t OFF_ZP  = OFF_WHJ + 32 * 1024;                // 256 KiB (8*8192*4)
    const size_t OFF_AP  = OFF_ZP + 512 * 1024;                // 32 MiB
    const size_t OFF_WHT = OFF_AP + (size_t)JSPLIT * NN * HH * 4;
    const size_t NEED    = OFF_WHT + (size_t)2 * 1024 * 1024;  // ~39 MiB

    const bool fits = (ws_size >= NEED);
    // fallback: borrow the edge region of d_out (overwritten only at the end)
    char* scratch = fits ? (char*)d_ws : (char*)d_out + (size_t)NN * HH * 4;
    float* Wh   = (float*)(scratch + OFF_WH);
    float* Whi  = (float*)(scratch + OFF_WHI);
    float* Whj  = (float*)(scratch + OFF_WHJ);
    float* Zp   = (float*)(scratch + OFF_ZP);
    float* accP = (float*)(scratch + OFF_AP);
    u16*   WhT  = (u16*)(scratch + OFF_WHT);
    f32x4* edst = (f32x4*)(out + (size_t)NN * HH);

    k_pre<<<dim3(256), 256, 0, stream>>>(node, Ww, Wb, a1, a2, Wh, WhT, Whi, Whj);
    k_main<<<dim3(COPY_BLOCKS + ATTN_BLOCKS), 256, 0, stream>>>(
        adj, WhT, Whi, Whj, (const f32x4*)edge, edst, accP, Zp, fits ? 1 : 0);
    k_red<<<dim3(1024), 256, 0, stream>>>(accP, Zp, Wh, out);
    if (!fits)
        k_copy<<<dim3(4096), 256, 0, stream>>>((const f32x4*)edge, edst, NN * NN / 4);
}